// Round 4
// baseline (40.935 us; speedup 1.0000x reference)
//
#include <hip/hip_runtime.h>

// out[b, n, s, e] = in[b, s + n - 2, e]  (0 if src row out of range)
// B=8, S=2048, E=512, N=5. fp32, vectorized 16B (E4 = 128 vec4 per row).
//
// SCATTER formulation: thread i loads input vec4 i ONCE, stores it to the
// 5 output rows it contributes to. Both streams are pure streaming ->
// non-temporal hints to skip cache allocation.
// Boundary-zero rows (6 per batch) are written by 24 extra fused blocks.

typedef float v4f __attribute__((ext_vector_type(4)));

#define NG_S 2048
#define NG_E4 128
#define NBLK_MAIN 8192   // 8*2048*128 / 256
#define NBLK_ZERO 24     // 8 batches * 6 rows * 128 vec4 / 256

__global__ __launch_bounds__(256) void ngram_scatter(const v4f* __restrict__ in,
                                                     v4f* __restrict__ out) {
    const unsigned bid = blockIdx.x;
    if (bid < NBLK_MAIN) {
        const unsigned i  = bid * 256u + threadIdx.x;   // input vec4 index
        const unsigned e4 = i & (NG_E4 - 1);
        const unsigned t  = i >> 7;                      // b*2048 + s_src
        const unsigned s  = t & (NG_S - 1);
        const unsigned b  = t >> 11;
        const v4f v = __builtin_nontemporal_load(&in[i]);
        const unsigned bn = b * 5u;
        #pragma unroll
        for (int n = 0; n < 5; ++n) {
            const int s_out = (int)s + 2 - n;            // wave-uniform branch
            if (s_out >= 0 && s_out < (int)NG_S) {
                v4f* p = &out[((((bn + (unsigned)n) << 11) + (unsigned)s_out) << 7) + e4];
                __builtin_nontemporal_store(v, p);
            }
        }
    } else {
        // zero-fill the 6 out-of-range rows per batch
        const unsigned j  = (bid - NBLK_MAIN) * 256u + threadIdx.x;  // < 6144
        const unsigned e4 = j & (NG_E4 - 1);
        const unsigned r  = j >> 7;                      // < 48
        const unsigned b  = r / 6u;
        const unsigned k  = r - b * 6u;
        unsigned n, sx;
        switch (k) {
            case 0: n = 0; sx = 0;    break;
            case 1: n = 0; sx = 1;    break;
            case 2: n = 1; sx = 0;    break;
            case 3: n = 3; sx = 2047; break;
            case 4: n = 4; sx = 2046; break;
            default: n = 4; sx = 2047; break;
        }
        v4f* p = &out[((((b * 5u + n) << 11) + sx) << 7) + e4];
        const v4f z = {0.f, 0.f, 0.f, 0.f};
        __builtin_nontemporal_store(z, p);
    }
}

extern "C" void kernel_launch(void* const* d_in, const int* in_sizes, int n_in,
                              void* d_out, int out_size, void* d_ws, size_t ws_size,
                              hipStream_t stream) {
    const v4f* in = (const v4f*)d_in[0];
    v4f* out = (v4f*)d_out;
    ngram_scatter<<<NBLK_MAIN + NBLK_ZERO, 256, 0, stream>>>(in, out);
}

// Round 5
// 34.495 us; speedup vs baseline: 1.1867x; 1.1867x over previous
//
#include <hip/hip_runtime.h>

// out[b, n, s, e] = in[b, s + n - 2, e]  (0 if src row out of range)
// B=8, S=2048, E=512, N=5. fp32, vectorized as float4 (E4 = 128 per row).
//
// SCATTER formulation: thread i loads input float4 i once, stores it to the
// 5 output rows it contributes to (all stores coalesced per-wave).
// Boundary-zero rows (6 per batch) are written by 24 extra fused blocks.
// NOTE: __builtin_nontemporal_* measured -18% here (R3/R4) — keep cached ops.

#define NG_S 2048
#define NG_E4 128
#define NBLK_MAIN 8192   // 8*2048*128 / 256
#define NBLK_ZERO 24     // 8 batches * 6 rows * 128 float4 / 256

__global__ __launch_bounds__(256) void ngram_scatter(const float4* __restrict__ in,
                                                     float4* __restrict__ out) {
    const unsigned bid = blockIdx.x;
    if (bid < NBLK_MAIN) {
        const unsigned i  = bid * 256u + threadIdx.x;   // input float4 index
        const unsigned e4 = i & (NG_E4 - 1);
        const unsigned t  = i >> 7;                      // b*2048 + s_src
        const unsigned s  = t & (NG_S - 1);
        const unsigned b  = t >> 11;
        const float4 v = in[i];
        const unsigned bn = b * 5u;
        #pragma unroll
        for (int n = 0; n < 5; ++n) {
            const int s_out = (int)s + 2 - n;            // wave-uniform branch
            if (s_out >= 0 && s_out < (int)NG_S) {
                out[((((bn + (unsigned)n) << 11) + (unsigned)s_out) << 7) + e4] = v;
            }
        }
    } else {
        // zero-fill the 6 out-of-range rows per batch
        const unsigned j  = (bid - NBLK_MAIN) * 256u + threadIdx.x;  // < 6144
        const unsigned e4 = j & (NG_E4 - 1);
        const unsigned r  = j >> 7;                      // < 48
        const unsigned b  = r / 6u;
        const unsigned k  = r - b * 6u;
        unsigned n, sx;
        switch (k) {
            case 0: n = 0; sx = 0;    break;
            case 1: n = 0; sx = 1;    break;
            case 2: n = 1; sx = 0;    break;
            case 3: n = 3; sx = 2047; break;
            case 4: n = 4; sx = 2046; break;
            default: n = 4; sx = 2047; break;
        }
        out[((((b * 5u + n) << 11) + sx) << 7) + e4] = make_float4(0.f, 0.f, 0.f, 0.f);
    }
}

extern "C" void kernel_launch(void* const* d_in, const int* in_sizes, int n_in,
                              void* d_out, int out_size, void* d_ws, size_t ws_size,
                              hipStream_t stream) {
    const float4* in = (const float4*)d_in[0];
    float4* out = (float4*)d_out;
    ngram_scatter<<<NBLK_MAIN + NBLK_ZERO, 256, 0, stream>>>(in, out);
}